// Round 1
// baseline (1091.854 us; speedup 1.0000x reference)
//
#include <hip/hip_runtime.h>

#define DD 128
#define HH 8

__device__ __forceinline__ unsigned f2key(float f) {
  unsigned u = __float_as_uint(f);
  return (u & 0x80000000u) ? ~u : (u | 0x80000000u);
}
__device__ __forceinline__ float key2f(unsigned k) {
  unsigned u = (k & 0x80000000u) ? (k ^ 0x80000000u) : ~k;
  return __uint_as_float(u);
}
__device__ __forceinline__ void atomAddF(float* p, float v) {
#if defined(__HIP_DEVICE_COMPILE__)
  unsafeAtomicAdd(p, v);
#else
  atomicAdd(p, v);
#endif
}

// xl = x@Wl + bl ; xr = x@Wr + br. Both W in LDS; 2 rows in flight.
__global__ __launch_bounds__(256) void k_xlxr(const float* __restrict__ x,
    const float* __restrict__ Wl, const float* __restrict__ bl,
    const float* __restrict__ Wr, const float* __restrict__ br,
    float* __restrict__ xl, float* __restrict__ xr, int N) {
  __shared__ float sW[2][DD][DD];
  __shared__ float sx[2][DD];
  for (int i = threadIdx.x; i < DD * DD; i += 256) {
    sW[0][i >> 7][i & 127] = Wl[i];
    sW[1][i >> 7][i & 127] = Wr[i];
  }
  int col = threadIdx.x & 127;
  int side = threadIdx.x >> 7;
  float bias = side ? br[col] : bl[col];
  float* dst = side ? xr : xl;
  __syncthreads();
  for (int r = blockIdx.x * 2; r < N; r += gridDim.x * 2) {
    __syncthreads();
    int rr = threadIdx.x >> 7;
    if (r + rr < N) sx[rr][col] = x[(size_t)(r + rr) * DD + col];
    __syncthreads();
    float a0 = bias, a1 = bias;
#pragma unroll
    for (int k = 0; k < DD; k++) {
      float w = sW[side][k][col];
      a0 += sx[0][k] * w;
      a1 += sx[1][k] * w;
    }
    dst[(size_t)r * DD + col] = a0;
    if (r + 1 < N) dst[(size_t)(r + 1) * DD + col] = a1;
  }
}

// Per edge (wave): logits[e,h] = sum_c lrelu(xl[s]+xr[d])*att ; atomicMax m.
__global__ __launch_bounds__(256) void k_logits(const float* __restrict__ xl,
    const float* __restrict__ xr, const int* __restrict__ ei,
    const float* __restrict__ att, float* __restrict__ logits,
    unsigned* __restrict__ mkey, int E, int N) {
  int lane = threadIdx.x & 63;
  int wid = (blockIdx.x * 256 + threadIdx.x) >> 6;
  int nw = (gridDim.x * 256) >> 6;
  int Et = E + N;
  float a0 = att[lane], a1 = att[lane + 64];
  for (int e = wid; e < Et; e += nw) {
    int s, d;
    if (e < E) { s = ei[e]; d = ei[E + e]; } else { s = e - E; d = s; }
    const float* pl = xl + (size_t)s * DD;
    const float* pr = xr + (size_t)d * DD;
    float v0 = pl[lane] + pr[lane];
    float v1 = pl[lane + 64] + pr[lane + 64];
    v0 = (v0 > 0.f ? v0 : 0.2f * v0) * a0;
    v1 = (v1 > 0.f ? v1 : 0.2f * v1) * a1;
#pragma unroll
    for (int o = 8; o; o >>= 1) { v0 += __shfl_xor(v0, o); v1 += __shfl_xor(v1, o); }
    if ((lane & 15) == 0) {
      int h = lane >> 4;
      logits[(size_t)e * HH + h] = v0;
      logits[(size_t)e * HH + 4 + h] = v1;
      atomicMax(&mkey[(size_t)d * HH + h], f2key(v0));
      atomicMax(&mkey[(size_t)d * HH + 4 + h], f2key(v1));
    }
  }
}

// Per edge: ex=exp(logit-m); denom += ex; acc[dst] += ex*xl[src]
__global__ __launch_bounds__(256) void k_scatter(const float* __restrict__ xl,
    const int* __restrict__ ei, const float* __restrict__ logits,
    const unsigned* __restrict__ mkey, float* __restrict__ denom,
    float* __restrict__ acc, int E, int N) {
  int lane = threadIdx.x & 63;
  int wid = (blockIdx.x * 256 + threadIdx.x) >> 6;
  int nw = (gridDim.x * 256) >> 6;
  int Et = E + N;
  for (int e = wid; e < Et; e += nw) {
    int s, d;
    if (e < E) { s = ei[e]; d = ei[E + e]; } else { s = e - E; d = s; }
    float ex = 0.f;
    if (lane < HH) {
      float m = key2f(mkey[(size_t)d * HH + lane]);
      ex = __expf(logits[(size_t)e * HH + lane] - m);
      atomAddF(&denom[(size_t)d * HH + lane], ex);
    }
    float ex0 = __shfl(ex, lane >> 4);
    float ex1 = __shfl(ex, 4 + (lane >> 4));
    const float* ps = xl + (size_t)s * DD;
    float* pa = acc + (size_t)d * DD;
    atomAddF(&pa[lane], ex0 * ps[lane]);
    atomAddF(&pa[lane + 64], ex1 * ps[lane + 64]);
  }
}

// Hfeat = relu(acc/denom + conv_bias) in place; per-channel sum/sumsq.
__global__ __launch_bounds__(256) void k_hbn(float* __restrict__ acc,
    const float* __restrict__ denom, const float* __restrict__ cb,
    float* __restrict__ bnsum, int N) {
  int col = threadIdx.x & 127;
  int half = threadIdx.x >> 7;
  int rowStart = blockIdx.x * 2 + half;
  int stride = gridDim.x * 2;
  float c = cb[col];
  int h = col >> 4;
  float s = 0.f, ss = 0.f;
  for (int r = rowStart; r < N; r += stride) {
    float den = denom[(size_t)r * HH + h] + 1e-16f;
    float v = acc[(size_t)r * DD + col] / den + c;
    v = fmaxf(v, 0.f);
    acc[(size_t)r * DD + col] = v;
    s += v;
    ss += v * v;
  }
  __shared__ float ls[256], lss[256];
  ls[threadIdx.x] = s;
  lss[threadIdx.x] = ss;
  __syncthreads();
  if (threadIdx.x < 128) {
    atomAddF(&bnsum[col], ls[threadIdx.x] + ls[threadIdx.x + 128]);
    atomAddF(&bnsum[DD + col], lss[threadIdx.x] + lss[threadIdx.x + 128]);
  }
}

// BN stats -> scale/shift; fold into b1' and b2''.
__global__ __launch_bounds__(128) void k_bnfold(const float* __restrict__ bnsum,
    const float* __restrict__ gamma, const float* __restrict__ beta,
    const float* __restrict__ linW, const float* __restrict__ linb,
    const float* __restrict__ dec2W, const float* __restrict__ dec2b,
    float* __restrict__ scale, float* __restrict__ shift,
    float* __restrict__ b1p, float* __restrict__ b2pp, int N) {
  int t = threadIdx.x;
  __shared__ float sshift[DD], sb1[DD];
  float mean = bnsum[t] / (float)N;
  float var = bnsum[DD + t] / (float)N - mean * mean;
  float sc = gamma[t] / sqrtf(var + 1e-5f);
  float sh = beta[t] - mean * sc;
  scale[t] = sc;
  shift[t] = sh;
  sshift[t] = sh;
  __syncthreads();
  float b1 = linb[t];
  for (int k = 0; k < DD; k++) b1 += sshift[k] * linW[k * DD + t];
  b1p[t] = b1;
  sb1[t] = b1;
  __syncthreads();
  float b2 = dec2b[t];
  for (int k = 0; k < DD; k++) b2 += sb1[k] * dec2W[k * DD + t];
  b2pp[t] = b2;
}

// W2''[d][j] = scale[d] * sum_k linW[d][k]*dec2W[k][j]
__global__ __launch_bounds__(256) void k_w2pp(const float* __restrict__ scale,
    const float* __restrict__ linW, const float* __restrict__ dec2W,
    float* __restrict__ W2pp) {
  int t = blockIdx.x * 256 + threadIdx.x;
  int dd = t >> 7, j = t & 127;
  float s = 0.f;
  for (int k = 0; k < DD; k++) s += linW[dd * DD + k] * dec2W[k * DD + j];
  W2pp[t] = scale[dd] * s;
}

// z = Hfeat@W1' + b1' ; v2 = Hfeat@W2'' + b2'' (one pass over Hfeat).
__global__ __launch_bounds__(256) void k_zv2(const float* __restrict__ hfeat,
    const float* __restrict__ linW, const float* __restrict__ scale,
    const float* __restrict__ b1p, const float* __restrict__ W2pp,
    const float* __restrict__ b2pp, float* __restrict__ z,
    float* __restrict__ v2, int N) {
  __shared__ float sW[2][DD][DD];
  __shared__ float sx[2][DD];
  for (int i = threadIdx.x; i < DD * DD; i += 256) {
    int k = i >> 7, j = i & 127;
    sW[0][k][j] = scale[k] * linW[i];
    sW[1][k][j] = W2pp[i];
  }
  int col = threadIdx.x & 127;
  int side = threadIdx.x >> 7;
  float bias = side ? b2pp[col] : b1p[col];
  float* dst = side ? v2 : z;
  __syncthreads();
  for (int r = blockIdx.x * 2; r < N; r += gridDim.x * 2) {
    __syncthreads();
    int rr = threadIdx.x >> 7;
    if (r + rr < N) sx[rr][col] = hfeat[(size_t)(r + rr) * DD + col];
    __syncthreads();
    float a0 = bias, a1 = bias;
#pragma unroll
    for (int k = 0; k < DD; k++) {
      float w = sW[side][k][col];
      a0 += sx[0][k] * w;
      a1 += sx[1][k] * w;
    }
    dst[(size_t)r * DD + col] = a0;
    if (r + 1 < N) dst[(size_t)(r + 1) * DD + col] = a1;
  }
}

// value1[e] = sigmoid(-(relu(a)*dist + b)) = 1/(1+exp(a*dist+b))
__global__ __launch_bounds__(256) void k_edge(const float* __restrict__ z,
    const int* __restrict__ ei, const float* __restrict__ ae,
    const float* __restrict__ be, float* __restrict__ v1, int E) {
  int lane = threadIdx.x & 63;
  int wid = (blockIdx.x * 256 + threadIdx.x) >> 6;
  int nw = (gridDim.x * 256) >> 6;
  float a = fmaxf(ae[0], 0.f), b = be[0];
  for (int e = wid; e < E; e += nw) {
    int s = ei[e], d = ei[E + e];
    const float* ps = z + (size_t)s * DD;
    const float* pd = z + (size_t)d * DD;
    float d0 = ps[lane] - pd[lane];
    float d1 = ps[lane + 64] - pd[lane + 64];
    float v = d0 * d0 + d1 * d1;
#pragma unroll
    for (int o = 32; o; o >>= 1) v += __shfl_xor(v, o);
    if (lane == 0) v1[e] = 1.f / (1.f + __expf(fmaf(a, v, b)));
  }
}

extern "C" void kernel_launch(void* const* d_in, const int* in_sizes, int n_in,
                              void* d_out, int out_size, void* d_ws, size_t ws_size,
                              hipStream_t stream) {
  const float* x = (const float*)d_in[0];
  const int* ei = (const int*)d_in[1];
  const float* Wl = (const float*)d_in[2];
  const float* bl = (const float*)d_in[3];
  const float* Wr = (const float*)d_in[4];
  const float* br = (const float*)d_in[5];
  const float* att = (const float*)d_in[6];
  const float* cb = (const float*)d_in[7];
  const float* gamma = (const float*)d_in[8];
  const float* beta = (const float*)d_in[9];
  const float* linW = (const float*)d_in[10];
  const float* linb = (const float*)d_in[11];
  const float* ae = (const float*)d_in[12];
  const float* be = (const float*)d_in[13];
  const float* dec2W = (const float*)d_in[14];
  const float* dec2b = (const float*)d_in[15];

  int N = in_sizes[0] / DD;
  int E = in_sizes[1] / 2;
  int Et = E + N;

  float* ws = (float*)d_ws;
  size_t o = 0;
  float* xl = ws + o;   o += (size_t)N * DD;
  float* xr = ws + o;   o += (size_t)N * DD;
  float* acc = ws + o;  o += (size_t)N * DD;
  float* logits = ws + o; o += (size_t)Et * HH;
  unsigned* mkey = (unsigned*)(ws + o); o += (size_t)N * HH;
  float* denom = ws + o; o += (size_t)N * HH;
  float* bnsum = ws + o; o += 2 * DD;
  float* scale = ws + o; o += DD;
  float* shift = ws + o; o += DD;
  float* b1p = ws + o;  o += DD;
  float* b2pp = ws + o; o += DD;
  float* W2pp = ws + o; o += DD * DD;

  float* z = (float*)d_out;
  float* v1 = z + (size_t)N * DD;
  float* v2 = v1 + E;

  hipMemsetAsync(mkey, 0, (size_t)N * HH * 4, stream);
  hipMemsetAsync(denom, 0, (size_t)N * HH * 4, stream);
  hipMemsetAsync(acc, 0, (size_t)N * DD * 4, stream);
  hipMemsetAsync(bnsum, 0, 2 * DD * 4, stream);

  k_xlxr<<<512, 256, 0, stream>>>(x, Wl, bl, Wr, br, xl, xr, N);
  k_logits<<<2048, 256, 0, stream>>>(xl, xr, ei, att, logits, mkey, E, N);
  k_scatter<<<2048, 256, 0, stream>>>(xl, ei, logits, mkey, denom, acc, E, N);
  k_hbn<<<256, 256, 0, stream>>>(acc, denom, cb, bnsum, N);
  k_bnfold<<<1, 128, 0, stream>>>(bnsum, gamma, beta, linW, linb, dec2W, dec2b,
                                  scale, shift, b1p, b2pp, N);
  k_w2pp<<<64, 256, 0, stream>>>(scale, linW, dec2W, W2pp);
  k_zv2<<<512, 256, 0, stream>>>(acc, linW, scale, b1p, W2pp, b2pp, z, v2, N);
  k_edge<<<2048, 256, 0, stream>>>(z, ei, ae, be, v1, E);
}

// Round 2
// 853.526 us; speedup vs baseline: 1.2792x; 1.2792x over previous
//
#include <hip/hip_runtime.h>

#define DD 128
#define HH 8

__device__ __forceinline__ void atomAddF(float* p, float v) {
#if defined(__HIP_DEVICE_COMPILE__)
  unsafeAtomicAdd(p, v);
#else
  atomicAdd(p, v);
#endif
}
__device__ __forceinline__ float lrelu(float v) { return v > 0.f ? v : 0.2f * v; }

// xl = x@Wl + bl ; xr = x@Wr + br. Both W in LDS; 2 rows in flight.
__global__ __launch_bounds__(256) void k_xlxr(const float* __restrict__ x,
    const float* __restrict__ Wl, const float* __restrict__ bl,
    const float* __restrict__ Wr, const float* __restrict__ br,
    float* __restrict__ xl, float* __restrict__ xr, int N) {
  __shared__ float sW[2][DD][DD];
  __shared__ float sx[2][DD];
  for (int i = threadIdx.x; i < DD * DD; i += 256) {
    sW[0][i >> 7][i & 127] = Wl[i];
    sW[1][i >> 7][i & 127] = Wr[i];
  }
  int col = threadIdx.x & 127;
  int side = threadIdx.x >> 7;
  float bias = side ? br[col] : bl[col];
  float* dst = side ? xr : xl;
  __syncthreads();
  for (int r = blockIdx.x * 2; r < N; r += gridDim.x * 2) {
    __syncthreads();
    int rr = threadIdx.x >> 7;
    if (r + rr < N) sx[rr][col] = x[(size_t)(r + rr) * DD + col];
    __syncthreads();
    float a0 = bias, a1 = bias;
#pragma unroll
    for (int k = 0; k < DD; k++) {
      float w = sW[side][k][col];
      a0 += sx[0][k] * w;
      a1 += sx[1][k] * w;
    }
    dst[(size_t)r * DD + col] = a0;
    if (r + 1 < N) dst[(size_t)(r + 1) * DD + col] = a1;
  }
}

__global__ __launch_bounds__(256) void k_deg(const int* __restrict__ ei,
    int* __restrict__ deg, int E) {
  int e = blockIdx.x * 256 + threadIdx.x;
  if (e < E) atomicAdd(&deg[ei[E + e]], 1);
}

// single-block exclusive scan of deg -> rowstart, cursor
__global__ __launch_bounds__(1024) void k_scan(const int* __restrict__ deg,
    int* __restrict__ rowstart, int* __restrict__ cursor, int N) {
  __shared__ int part[1024];
  int t = threadIdx.x;
  int chunk = (N + 1023) / 1024;
  int lo = t * chunk, hi = min(lo + chunk, N);
  int s = 0;
  for (int i = lo; i < hi; i++) s += deg[i];
  part[t] = s;
  __syncthreads();
  for (int off = 1; off < 1024; off <<= 1) {
    int v = (t >= off) ? part[t - off] : 0;
    __syncthreads();
    part[t] += v;
    __syncthreads();
  }
  if (t == 0) rowstart[N] = part[1023];
  int base = (t == 0) ? 0 : part[t - 1];
  for (int i = lo; i < hi; i++) {
    rowstart[i] = base;
    cursor[i] = base;
    base += deg[i];
  }
}

__global__ __launch_bounds__(256) void k_fill(const int* __restrict__ ei,
    int* __restrict__ cursor, int* __restrict__ csr_src, int E) {
  int e = blockIdx.x * 256 + threadIdx.x;
  if (e < E) {
    int d = ei[E + e];
    int pos = atomicAdd(&cursor[d], 1);
    csr_src[pos] = ei[e];
  }
}

// One wave per dst node. Online softmax over incoming edges + self-loop.
// Lane holds channels (2*lane, 2*lane+1); head = lane>>3 (8-lane groups).
// Writes final Hfeat = relu(out + conv_bias).
__global__ __launch_bounds__(256) void k_agg(const float* __restrict__ xl,
    const float* __restrict__ xr, const int* __restrict__ rowstart,
    const int* __restrict__ csr_src, const float* __restrict__ att,
    const float* __restrict__ cb, float* __restrict__ hfeat, int N) {
  int lane = threadIdx.x & 63;
  int d = (blockIdx.x * 256 + threadIdx.x) >> 6;
  if (d >= N) return;
  float2 a = ((const float2*)att)[lane];
  float2 r = ((const float2*)(xr + (size_t)d * DD))[lane];
  // self loop (src = dst)
  float2 g = ((const float2*)(xl + (size_t)d * DD))[lane];
  float t = lrelu(g.x + r.x) * a.x + lrelu(g.y + r.y) * a.y;
#pragma unroll
  for (int o = 4; o; o >>= 1) t += __shfl_xor(t, o);
  float m = t, den = 1.f;
  float2 acc = g;
  int i0 = rowstart[d], i1 = rowstart[d + 1];
  for (int i = i0; i < i1; i++) {
    int s = csr_src[i];
    g = ((const float2*)(xl + (size_t)s * DD))[lane];
    t = lrelu(g.x + r.x) * a.x + lrelu(g.y + r.y) * a.y;
#pragma unroll
    for (int o = 4; o; o >>= 1) t += __shfl_xor(t, o);
    if (t > m) {
      float sc = __expf(m - t);
      den = den * sc + 1.f;
      acc.x = acc.x * sc + g.x;
      acc.y = acc.y * sc + g.y;
      m = t;
    } else {
      float e = __expf(t - m);
      den += e;
      acc.x += e * g.x;
      acc.y += e * g.y;
    }
  }
  float2 c = ((const float2*)cb)[lane];
  float inv = 1.f / (den + 1e-16f);
  float2 o2;
  o2.x = fmaxf(fmaf(acc.x, inv, c.x), 0.f);
  o2.y = fmaxf(fmaf(acc.y, inv, c.y), 0.f);
  ((float2*)(hfeat + (size_t)d * DD))[lane] = o2;
}

// per-channel sum/sumsq of Hfeat (read-only)
__global__ __launch_bounds__(256) void k_hbn2(const float* __restrict__ hfeat,
    float* __restrict__ bnsum, int N) {
  int col = threadIdx.x & 127;
  float s = 0.f, ss = 0.f;
  for (int r = blockIdx.x * 2 + (threadIdx.x >> 7); r < N; r += gridDim.x * 2) {
    float v = hfeat[(size_t)r * DD + col];
    s += v;
    ss += v * v;
  }
  __shared__ float ls[256], lss[256];
  ls[threadIdx.x] = s;
  lss[threadIdx.x] = ss;
  __syncthreads();
  if (threadIdx.x < 128) {
    atomAddF(&bnsum[col], ls[threadIdx.x] + ls[threadIdx.x + 128]);
    atomAddF(&bnsum[DD + col], lss[threadIdx.x] + lss[threadIdx.x + 128]);
  }
}

// BN stats -> scale/shift; fold into b1' and b2''.
__global__ __launch_bounds__(128) void k_bnfold(const float* __restrict__ bnsum,
    const float* __restrict__ gamma, const float* __restrict__ beta,
    const float* __restrict__ linW, const float* __restrict__ linb,
    const float* __restrict__ dec2W, const float* __restrict__ dec2b,
    float* __restrict__ scale, float* __restrict__ shift,
    float* __restrict__ b1p, float* __restrict__ b2pp, int N) {
  int t = threadIdx.x;
  __shared__ float sshift[DD], sb1[DD];
  float mean = bnsum[t] / (float)N;
  float var = bnsum[DD + t] / (float)N - mean * mean;
  float sc = gamma[t] / sqrtf(var + 1e-5f);
  float sh = beta[t] - mean * sc;
  scale[t] = sc;
  shift[t] = sh;
  sshift[t] = sh;
  __syncthreads();
  float b1 = linb[t];
  for (int k = 0; k < DD; k++) b1 += sshift[k] * linW[k * DD + t];
  b1p[t] = b1;
  sb1[t] = b1;
  __syncthreads();
  float b2 = dec2b[t];
  for (int k = 0; k < DD; k++) b2 += sb1[k] * dec2W[k * DD + t];
  b2pp[t] = b2;
}

// W2''[d][j] = scale[d] * sum_k linW[d][k]*dec2W[k][j]
__global__ __launch_bounds__(256) void k_w2pp(const float* __restrict__ scale,
    const float* __restrict__ linW, const float* __restrict__ dec2W,
    float* __restrict__ W2pp) {
  int t = blockIdx.x * 256 + threadIdx.x;
  int dd = t >> 7, j = t & 127;
  float s = 0.f;
  for (int k = 0; k < DD; k++) s += linW[dd * DD + k] * dec2W[k * DD + j];
  W2pp[t] = scale[dd] * s;
}

// z = Hfeat@W1' + b1' ; v2 = Hfeat@W2'' + b2'' (one pass over Hfeat).
__global__ __launch_bounds__(256) void k_zv2(const float* __restrict__ hfeat,
    const float* __restrict__ linW, const float* __restrict__ scale,
    const float* __restrict__ b1p, const float* __restrict__ W2pp,
    const float* __restrict__ b2pp, float* __restrict__ z,
    float* __restrict__ v2, int N) {
  __shared__ float sW[2][DD][DD];
  __shared__ float sx[2][DD];
  for (int i = threadIdx.x; i < DD * DD; i += 256) {
    int k = i >> 7, j = i & 127;
    sW[0][k][j] = scale[k] * linW[i];
    sW[1][k][j] = W2pp[i];
  }
  int col = threadIdx.x & 127;
  int side = threadIdx.x >> 7;
  float bias = side ? b2pp[col] : b1p[col];
  float* dst = side ? v2 : z;
  __syncthreads();
  for (int r = blockIdx.x * 2; r < N; r += gridDim.x * 2) {
    __syncthreads();
    int rr = threadIdx.x >> 7;
    if (r + rr < N) sx[rr][col] = hfeat[(size_t)(r + rr) * DD + col];
    __syncthreads();
    float a0 = bias, a1 = bias;
#pragma unroll
    for (int k = 0; k < DD; k++) {
      float w = sW[side][k][col];
      a0 += sx[0][k] * w;
      a1 += sx[1][k] * w;
    }
    dst[(size_t)r * DD + col] = a0;
    if (r + 1 < N) dst[(size_t)(r + 1) * DD + col] = a1;
  }
}

// value1[e] = 1/(1+exp(a*dist+b)), wave per edge, float2 lanes
__global__ __launch_bounds__(256) void k_edge(const float* __restrict__ z,
    const int* __restrict__ ei, const float* __restrict__ ae,
    const float* __restrict__ be, float* __restrict__ v1, int E) {
  int lane = threadIdx.x & 63;
  int wid = (blockIdx.x * 256 + threadIdx.x) >> 6;
  int nw = (gridDim.x * 256) >> 6;
  float a = fmaxf(ae[0], 0.f), b = be[0];
  for (int e = wid; e < E; e += nw) {
    int s = ei[e], d = ei[E + e];
    float2 zs = ((const float2*)(z + (size_t)s * DD))[lane];
    float2 zd = ((const float2*)(z + (size_t)d * DD))[lane];
    float dx = zs.x - zd.x, dy = zs.y - zd.y;
    float v = dx * dx + dy * dy;
#pragma unroll
    for (int o = 32; o; o >>= 1) v += __shfl_xor(v, o);
    if (lane == 0) v1[e] = 1.f / (1.f + __expf(fmaf(a, v, b)));
  }
}

extern "C" void kernel_launch(void* const* d_in, const int* in_sizes, int n_in,
                              void* d_out, int out_size, void* d_ws, size_t ws_size,
                              hipStream_t stream) {
  const float* x = (const float*)d_in[0];
  const int* ei = (const int*)d_in[1];
  const float* Wl = (const float*)d_in[2];
  const float* bl = (const float*)d_in[3];
  const float* Wr = (const float*)d_in[4];
  const float* br = (const float*)d_in[5];
  const float* att = (const float*)d_in[6];
  const float* cb = (const float*)d_in[7];
  const float* gamma = (const float*)d_in[8];
  const float* beta = (const float*)d_in[9];
  const float* linW = (const float*)d_in[10];
  const float* linb = (const float*)d_in[11];
  const float* ae = (const float*)d_in[12];
  const float* be = (const float*)d_in[13];
  const float* dec2W = (const float*)d_in[14];
  const float* dec2b = (const float*)d_in[15];

  int N = in_sizes[0] / DD;
  int E = in_sizes[1] / 2;

  float* ws = (float*)d_ws;
  size_t o = 0;
  float* xl = ws + o;    o += (size_t)N * DD;
  float* xr = ws + o;    o += (size_t)N * DD;
  float* hfeat = ws + o; o += (size_t)N * DD;
  float* bnsum = ws + o; o += 2 * DD;
  float* scale = ws + o; o += DD;
  float* shift = ws + o; o += DD;
  float* b1p = ws + o;   o += DD;
  float* b2pp = ws + o;  o += DD;
  float* W2pp = ws + o;  o += DD * DD;
  int* deg = (int*)(ws + o);      o += N + 1;
  int* rowstart = (int*)(ws + o); o += N + 1;
  int* cursor = (int*)(ws + o);   o += N;
  int* csr_src = (int*)(ws + o);  o += E;

  float* z = (float*)d_out;
  float* v1 = z + (size_t)N * DD;
  float* v2 = v1 + E;

  hipMemsetAsync(deg, 0, (size_t)(N + 1) * 4, stream);
  hipMemsetAsync(bnsum, 0, 2 * DD * 4, stream);

  k_deg<<<(E + 255) / 256, 256, 0, stream>>>(ei, deg, E);
  k_scan<<<1, 1024, 0, stream>>>(deg, rowstart, cursor, N);
  k_fill<<<(E + 255) / 256, 256, 0, stream>>>(ei, cursor, csr_src, E);
  k_xlxr<<<512, 256, 0, stream>>>(x, Wl, bl, Wr, br, xl, xr, N);
  k_agg<<<(N + 3) / 4, 256, 0, stream>>>(xl, xr, rowstart, csr_src, att, cb,
                                         hfeat, N);
  k_hbn2<<<256, 256, 0, stream>>>(hfeat, bnsum, N);
  k_bnfold<<<1, 128, 0, stream>>>(bnsum, gamma, beta, linW, linb, dec2W, dec2b,
                                  scale, shift, b1p, b2pp, N);
  k_w2pp<<<64, 256, 0, stream>>>(scale, linW, dec2W, W2pp);
  k_zv2<<<512, 256, 0, stream>>>(hfeat, linW, scale, b1p, W2pp, b2pp, z, v2, N);
  k_edge<<<2048, 256, 0, stream>>>(z, ei, ae, be, v1, E);
}

// Round 3
// 493.656 us; speedup vs baseline: 2.2118x; 1.7290x over previous
//
#include <hip/hip_runtime.h>

#define DD 128
#define HH 8

typedef float f32x4 __attribute__((ext_vector_type(4)));
typedef short s16x8 __attribute__((ext_vector_type(8)));

__device__ __forceinline__ ushort f2b(float f) {
  unsigned u = __float_as_uint(f);
  unsigned r = u + 0x7fffu + ((u >> 16) & 1u);
  return (ushort)(r >> 16);
}
__device__ __forceinline__ float b2f(ushort b) {
  return __uint_as_float(((unsigned)b) << 16);
}
__device__ __forceinline__ void atomAddF(float* p, float v) {
#if defined(__HIP_DEVICE_COMPILE__)
  unsafeAtomicAdd(p, v);
#else
  atomicAdd(p, v);
#endif
}
__device__ __forceinline__ float lrelu(float v) { return v > 0.f ? v : 0.2f * v; }

// ---------- CSR build ----------
__global__ __launch_bounds__(256) void k_deg(const int* __restrict__ ei,
    int* __restrict__ deg, int E) {
  int e = blockIdx.x * 256 + threadIdx.x;
  if (e < E) atomicAdd(&deg[ei[E + e]], 1);
}

__global__ __launch_bounds__(1024) void k_scan(const int* __restrict__ deg,
    int* __restrict__ rowstart, int* __restrict__ cursor, int N) {
  __shared__ int part[1024];
  int t = threadIdx.x;
  int chunk = (N + 1023) / 1024;
  int lo = t * chunk, hi = min(lo + chunk, N);
  int s = 0;
  for (int i = lo; i < hi; i++) s += deg[i];
  part[t] = s;
  __syncthreads();
  for (int off = 1; off < 1024; off <<= 1) {
    int v = (t >= off) ? part[t - off] : 0;
    __syncthreads();
    part[t] += v;
    __syncthreads();
  }
  if (t == 0) rowstart[N] = part[1023];
  int base = (t == 0) ? 0 : part[t - 1];
  for (int i = lo; i < hi; i++) {
    rowstart[i] = base;
    cursor[i] = base;
    base += deg[i];
  }
}

__global__ __launch_bounds__(256) void k_fill(const int* __restrict__ ei,
    int* __restrict__ cursor, int* __restrict__ csr_src, int E) {
  int e = blockIdx.x * 256 + threadIdx.x;
  if (e < E) {
    int d = ei[E + e];
    int pos = atomicAdd(&cursor[d], 1);
    csr_src[pos] = ei[e];
  }
}

// ---------- conversions / packing ----------
__global__ __launch_bounds__(256) void k_convx(const float* __restrict__ x,
    ushort* __restrict__ xb, int total4) {
  int i = blockIdx.x * 256 + threadIdx.x;
  if (i >= total4) return;
  float4 v = ((const float4*)x)[i];
  ushort4 o;
  o.x = f2b(v.x); o.y = f2b(v.y); o.z = f2b(v.z); o.w = f2b(v.w);
  ((ushort4*)xb)[i] = o;
}

// pack W[k][n] (128x128 row-major) into B-fragment order for 16x16x32 MFMA:
// P[((q*8+c)*64 + l)*8 + j] = W[q*32 + (l>>4)*8 + j][c*16 + (l&15)]
__device__ __forceinline__ void packW_idx(int i, int& k, int& n) {
  int j = i & 7, l = (i >> 3) & 63, tile = i >> 9;
  int q = tile >> 3, c = tile & 7;
  k = q * 32 + ((l >> 4) << 3) + j;
  n = c * 16 + (l & 15);
}

__global__ __launch_bounds__(256) void k_packWlr(const float* __restrict__ Wl,
    const float* __restrict__ Wr, ushort* __restrict__ WlP,
    ushort* __restrict__ WrP) {
  int t = blockIdx.x * 256 + threadIdx.x;  // 32768
  int side = t >> 14;
  int i = t & 16383;
  int k, n;
  packW_idx(i, k, n);
  if (side) WrP[i] = f2b(Wr[k * DD + n]);
  else      WlP[i] = f2b(Wl[k * DD + n]);
}

__global__ __launch_bounds__(256) void k_packW2(const float* __restrict__ linW,
    const float* __restrict__ scale, const float* __restrict__ W2pp,
    ushort* __restrict__ W1P, ushort* __restrict__ W2P) {
  int t = blockIdx.x * 256 + threadIdx.x;  // 32768
  int side = t >> 14;
  int i = t & 16383;
  int k, n;
  packW_idx(i, k, n);
  if (side) W2P[i] = f2b(W2pp[k * DD + n]);
  else      W1P[i] = f2b(scale[k] * linW[k * DD + n]);
}

// ---------- MFMA GEMM: out_l/out_r (bf16) = A @ Wl/Wr + bias ----------
__global__ __launch_bounds__(256) void k_mm_lr(const ushort* __restrict__ xb,
    const ushort* __restrict__ WlP, const ushort* __restrict__ WrP,
    const float* __restrict__ bl, const float* __restrict__ br,
    ushort* __restrict__ xlb, ushort* __restrict__ xrb, int N) {
  __shared__ ushort sW[2][16384];
  {
    const uint4* a = (const uint4*)WlP;
    const uint4* b = (const uint4*)WrP;
    uint4* da = (uint4*)sW[0];
    uint4* db = (uint4*)sW[1];
    for (int i = threadIdx.x; i < 2048; i += 256) { da[i] = a[i]; db[i] = b[i]; }
  }
  __syncthreads();
  int lane = threadIdx.x & 63;
  int wv = threadIdx.x >> 6;
  int rbase = blockIdx.x * 64 + wv * 16;
  int arow = rbase + (lane & 15);
  if (arow >= N) arow = 0;  // stores masked below
  const ushort* ap = xb + (size_t)arow * DD + ((lane >> 4) << 3);
  s16x8 afr[4];
#pragma unroll
  for (int q = 0; q < 4; q++) afr[q] = *(const s16x8*)(ap + q * 32);
  f32x4 accL[8] = {}, accR[8] = {};
#pragma unroll
  for (int q = 0; q < 4; q++) {
#pragma unroll
    for (int c = 0; c < 8; c++) {
      s16x8 bL = *(const s16x8*)(sW[0] + ((q * 8 + c) * 64 + lane) * 8);
      accL[c] = __builtin_amdgcn_mfma_f32_16x16x32_bf16(afr[q], bL, accL[c], 0, 0, 0);
      s16x8 bR = *(const s16x8*)(sW[1] + ((q * 8 + c) * 64 + lane) * 8);
      accR[c] = __builtin_amdgcn_mfma_f32_16x16x32_bf16(afr[q], bR, accR[c], 0, 0, 0);
    }
  }
  int r0 = rbase + ((lane >> 4) << 2);
  int colb = lane & 15;
#pragma unroll
  for (int c = 0; c < 8; c++) {
    int col = c * 16 + colb;
    float vbl = bl[col], vbr = br[col];
#pragma unroll
    for (int r = 0; r < 4; r++) {
      int row = r0 + r;
      if (row < N) {
        xlb[(size_t)row * DD + col] = f2b(accL[c][r] + vbl);
        xrb[(size_t)row * DD + col] = f2b(accR[c][r] + vbr);
      }
    }
  }
}

// ---------- MFMA GEMM: z (f32 + bf16 copy) and v2 (f32) from hfeat ----------
__global__ __launch_bounds__(256) void k_mm_z(const ushort* __restrict__ hfb,
    const ushort* __restrict__ W1P, const ushort* __restrict__ W2P,
    const float* __restrict__ b1p, const float* __restrict__ b2pp,
    float* __restrict__ z, ushort* __restrict__ zb, float* __restrict__ v2,
    int N) {
  __shared__ ushort sW[2][16384];
  {
    const uint4* a = (const uint4*)W1P;
    const uint4* b = (const uint4*)W2P;
    uint4* da = (uint4*)sW[0];
    uint4* db = (uint4*)sW[1];
    for (int i = threadIdx.x; i < 2048; i += 256) { da[i] = a[i]; db[i] = b[i]; }
  }
  __syncthreads();
  int lane = threadIdx.x & 63;
  int wv = threadIdx.x >> 6;
  int rbase = blockIdx.x * 64 + wv * 16;
  int arow = rbase + (lane & 15);
  if (arow >= N) arow = 0;
  const ushort* ap = hfb + (size_t)arow * DD + ((lane >> 4) << 3);
  s16x8 afr[4];
#pragma unroll
  for (int q = 0; q < 4; q++) afr[q] = *(const s16x8*)(ap + q * 32);
  f32x4 acc1[8] = {}, acc2[8] = {};
#pragma unroll
  for (int q = 0; q < 4; q++) {
#pragma unroll
    for (int c = 0; c < 8; c++) {
      s16x8 b1 = *(const s16x8*)(sW[0] + ((q * 8 + c) * 64 + lane) * 8);
      acc1[c] = __builtin_amdgcn_mfma_f32_16x16x32_bf16(afr[q], b1, acc1[c], 0, 0, 0);
      s16x8 b2 = *(const s16x8*)(sW[1] + ((q * 8 + c) * 64 + lane) * 8);
      acc2[c] = __builtin_amdgcn_mfma_f32_16x16x32_bf16(afr[q], b2, acc2[c], 0, 0, 0);
    }
  }
  int r0 = rbase + ((lane >> 4) << 2);
  int colb = lane & 15;
#pragma unroll
  for (int c = 0; c < 8; c++) {
    int col = c * 16 + colb;
    float vb1 = b1p[col], vb2 = b2pp[col];
#pragma unroll
    for (int r = 0; r < 4; r++) {
      int row = r0 + r;
      if (row < N) {
        float zv = acc1[c][r] + vb1;
        z[(size_t)row * DD + col] = zv;
        zb[(size_t)row * DD + col] = f2b(zv);
        v2[(size_t)row * DD + col] = acc2[c][r] + vb2;
      }
    }
  }
}

// ---------- GAT aggregation: wave/node, online softmax, bf16 gathers ----------
__global__ __launch_bounds__(256) void k_agg(const ushort* __restrict__ xlb,
    const ushort* __restrict__ xrb, const int* __restrict__ rowstart,
    const int* __restrict__ csr_src, const float* __restrict__ att,
    const float* __restrict__ cb, ushort* __restrict__ hfb, int N) {
  int lane = threadIdx.x & 63;
  int d = (blockIdx.x * 256 + threadIdx.x) >> 6;
  if (d >= N) return;
  float2 a = ((const float2*)att)[lane];
  ushort2 rv = ((const ushort2*)(xrb + (size_t)d * DD))[lane];
  float2 r = {b2f(rv.x), b2f(rv.y)};
  ushort2 gv = ((const ushort2*)(xlb + (size_t)d * DD))[lane];
  float2 g = {b2f(gv.x), b2f(gv.y)};
  float t = lrelu(g.x + r.x) * a.x + lrelu(g.y + r.y) * a.y;
#pragma unroll
  for (int o = 4; o; o >>= 1) t += __shfl_xor(t, o);
  float m = t, den = 1.f;
  float2 acc = g;
  int i0 = rowstart[d], i1 = rowstart[d + 1];
  for (int i = i0; i < i1; i++) {
    int s = csr_src[i];
    gv = ((const ushort2*)(xlb + (size_t)s * DD))[lane];
    g.x = b2f(gv.x); g.y = b2f(gv.y);
    t = lrelu(g.x + r.x) * a.x + lrelu(g.y + r.y) * a.y;
#pragma unroll
    for (int o = 4; o; o >>= 1) t += __shfl_xor(t, o);
    if (t > m) {
      float sc = __expf(m - t);
      den = den * sc + 1.f;
      acc.x = acc.x * sc + g.x;
      acc.y = acc.y * sc + g.y;
      m = t;
    } else {
      float e = __expf(t - m);
      den += e;
      acc.x += e * g.x;
      acc.y += e * g.y;
    }
  }
  float2 c = ((const float2*)cb)[lane];
  float inv = 1.f / (den + 1e-16f);
  ushort2 o2;
  o2.x = f2b(fmaxf(fmaf(acc.x, inv, c.x), 0.f));
  o2.y = f2b(fmaxf(fmaf(acc.y, inv, c.y), 0.f));
  ((ushort2*)(hfb + (size_t)d * DD))[lane] = o2;
}

// ---------- BN stats from bf16 hfeat ----------
__global__ __launch_bounds__(256) void k_hbn2(const ushort* __restrict__ hfb,
    float* __restrict__ bnsum, int N) {
  int col = threadIdx.x & 127;
  float s = 0.f, ss = 0.f;
  for (int r = blockIdx.x * 2 + (threadIdx.x >> 7); r < N; r += gridDim.x * 2) {
    float v = b2f(hfb[(size_t)r * DD + col]);
    s += v;
    ss += v * v;
  }
  __shared__ float ls[256], lss[256];
  ls[threadIdx.x] = s;
  lss[threadIdx.x] = ss;
  __syncthreads();
  if (threadIdx.x < 128) {
    atomAddF(&bnsum[col], ls[threadIdx.x] + ls[threadIdx.x + 128]);
    atomAddF(&bnsum[DD + col], lss[threadIdx.x] + lss[threadIdx.x + 128]);
  }
}

// ---------- BN fold ----------
__global__ __launch_bounds__(128) void k_bnfold(const float* __restrict__ bnsum,
    const float* __restrict__ gamma, const float* __restrict__ beta,
    const float* __restrict__ linW, const float* __restrict__ linb,
    const float* __restrict__ dec2W, const float* __restrict__ dec2b,
    float* __restrict__ scale, float* __restrict__ shift,
    float* __restrict__ b1p, float* __restrict__ b2pp, int N) {
  int t = threadIdx.x;
  __shared__ float sshift[DD], sb1[DD];
  float mean = bnsum[t] / (float)N;
  float var = bnsum[DD + t] / (float)N - mean * mean;
  float sc = gamma[t] / sqrtf(var + 1e-5f);
  float sh = beta[t] - mean * sc;
  scale[t] = sc;
  shift[t] = sh;
  sshift[t] = sh;
  __syncthreads();
  float b1 = linb[t];
  for (int k = 0; k < DD; k++) b1 += sshift[k] * linW[k * DD + t];
  b1p[t] = b1;
  sb1[t] = b1;
  __syncthreads();
  float b2 = dec2b[t];
  for (int k = 0; k < DD; k++) b2 += sb1[k] * dec2W[k * DD + t];
  b2pp[t] = b2;
}

// W2''[d][j] = scale[d] * sum_k linW[d][k]*dec2W[k][j]
__global__ __launch_bounds__(256) void k_w2pp(const float* __restrict__ scale,
    const float* __restrict__ linW, const float* __restrict__ dec2W,
    float* __restrict__ W2pp) {
  int t = blockIdx.x * 256 + threadIdx.x;
  int dd = t >> 7, j = t & 127;
  float s = 0.f;
  for (int k = 0; k < DD; k++) s += linW[dd * DD + k] * dec2W[k * DD + j];
  W2pp[t] = scale[dd] * s;
}

// ---------- edge decoder: bf16 z gathers ----------
__global__ __launch_bounds__(256) void k_edge(const ushort* __restrict__ zb,
    const int* __restrict__ ei, const float* __restrict__ ae,
    const float* __restrict__ be, float* __restrict__ v1, int E) {
  int lane = threadIdx.x & 63;
  int wid = (blockIdx.x * 256 + threadIdx.x) >> 6;
  int nw = (gridDim.x * 256) >> 6;
  float a = fmaxf(ae[0], 0.f), b = be[0];
  for (int e = wid; e < E; e += nw) {
    int s = ei[e], d = ei[E + e];
    ushort2 zs = ((const ushort2*)(zb + (size_t)s * DD))[lane];
    ushort2 zd = ((const ushort2*)(zb + (size_t)d * DD))[lane];
    float dx = b2f(zs.x) - b2f(zd.x), dy = b2f(zs.y) - b2f(zd.y);
    float v = dx * dx + dy * dy;
#pragma unroll
    for (int o = 32; o; o >>= 1) v += __shfl_xor(v, o);
    if (lane == 0) v1[e] = 1.f / (1.f + __expf(fmaf(a, v, b)));
  }
}

extern "C" void kernel_launch(void* const* d_in, const int* in_sizes, int n_in,
                              void* d_out, int out_size, void* d_ws, size_t ws_size,
                              hipStream_t stream) {
  const float* x = (const float*)d_in[0];
  const int* ei = (const int*)d_in[1];
  const float* Wl = (const float*)d_in[2];
  const float* bl = (const float*)d_in[3];
  const float* Wr = (const float*)d_in[4];
  const float* br = (const float*)d_in[5];
  const float* att = (const float*)d_in[6];
  const float* cb = (const float*)d_in[7];
  const float* gamma = (const float*)d_in[8];
  const float* beta = (const float*)d_in[9];
  const float* linW = (const float*)d_in[10];
  const float* linb = (const float*)d_in[11];
  const float* ae = (const float*)d_in[12];
  const float* be = (const float*)d_in[13];
  const float* dec2W = (const float*)d_in[14];
  const float* dec2b = (const float*)d_in[15];

  int N = in_sizes[0] / DD;
  int E = in_sizes[1] / 2;
  size_t ND = (size_t)N * DD;

  char* wsb = (char*)d_ws;
  size_t o = 0;
  auto alloc = [&](size_t bytes) {
    void* p = wsb + o;
    o += (bytes + 15) & ~(size_t)15;
    return p;
  };
  ushort* xb  = (ushort*)alloc(ND * 2);
  ushort* xlb = (ushort*)alloc(ND * 2);
  ushort* xrb = (ushort*)alloc(ND * 2);
  ushort* hfb = (ushort*)alloc(ND * 2);
  ushort* zbb = (ushort*)alloc(ND * 2);
  ushort* WlP = (ushort*)alloc(DD * DD * 2);
  ushort* WrP = (ushort*)alloc(DD * DD * 2);
  ushort* W1P = (ushort*)alloc(DD * DD * 2);
  ushort* W2P = (ushort*)alloc(DD * DD * 2);
  float* bnsum = (float*)alloc(2 * DD * 4);
  float* scale = (float*)alloc(DD * 4);
  float* shift = (float*)alloc(DD * 4);
  float* b1p   = (float*)alloc(DD * 4);
  float* b2pp  = (float*)alloc(DD * 4);
  float* W2pp  = (float*)alloc(DD * DD * 4);
  int* deg      = (int*)alloc((size_t)(N + 1) * 4);
  int* rowstart = (int*)alloc((size_t)(N + 1) * 4);
  int* cursor   = (int*)alloc((size_t)N * 4);
  int* csr_src  = (int*)alloc((size_t)E * 4);

  float* z = (float*)d_out;
  float* v1 = z + ND;
  float* v2 = v1 + E;

  hipMemsetAsync(deg, 0, (size_t)(N + 1) * 4, stream);
  hipMemsetAsync(bnsum, 0, 2 * DD * 4, stream);

  k_deg<<<(E + 255) / 256, 256, 0, stream>>>(ei, deg, E);
  k_scan<<<1, 1024, 0, stream>>>(deg, rowstart, cursor, N);
  k_fill<<<(E + 255) / 256, 256, 0, stream>>>(ei, cursor, csr_src, E);
  int total4 = (int)(ND / 4);
  k_convx<<<(total4 + 255) / 256, 256, 0, stream>>>(x, xb, total4);
  k_packWlr<<<128, 256, 0, stream>>>(Wl, Wr, WlP, WrP);
  k_mm_lr<<<(N + 63) / 64, 256, 0, stream>>>(xb, WlP, WrP, bl, br, xlb, xrb, N);
  k_agg<<<(N + 3) / 4, 256, 0, stream>>>(xlb, xrb, rowstart, csr_src, att, cb,
                                         hfb, N);
  k_hbn2<<<256, 256, 0, stream>>>(hfb, bnsum, N);
  k_bnfold<<<1, 128, 0, stream>>>(bnsum, gamma, beta, linW, linb, dec2W, dec2b,
                                  scale, shift, b1p, b2pp, N);
  k_w2pp<<<64, 256, 0, stream>>>(scale, linW, dec2W, W2pp);
  k_packW2<<<128, 256, 0, stream>>>(linW, scale, W2pp, W1P, W2P);
  k_mm_z<<<(N + 63) / 64, 256, 0, stream>>>(hfb, W1P, W2P, b1p, b2pp, z, zbb,
                                            v2, N);
  k_edge<<<2048, 256, 0, stream>>>(zbb, ei, ae, be, v1, E);
}

// Round 4
// 399.688 us; speedup vs baseline: 2.7318x; 1.2351x over previous
//
#include <hip/hip_runtime.h>

#define DD 128
#define HH 8

typedef float f32x4 __attribute__((ext_vector_type(4)));
typedef short s16x8 __attribute__((ext_vector_type(8)));

__device__ __forceinline__ ushort f2b(float f) {
  unsigned u = __float_as_uint(f);
  unsigned r = u + 0x7fffu + ((u >> 16) & 1u);
  return (ushort)(r >> 16);
}
__device__ __forceinline__ float b2f(ushort b) {
  return __uint_as_float(((unsigned)b) << 16);
}
__device__ __forceinline__ void atomAddF(float* p, float v) {
#if defined(__HIP_DEVICE_COMPILE__)
  unsafeAtomicAdd(p, v);
#else
  atomicAdd(p, v);
#endif
}
__device__ __forceinline__ float lrelu(float v) { return v > 0.f ? v : 0.2f * v; }

// ---------- CSR build ----------
__global__ __launch_bounds__(256) void k_deg(const int* __restrict__ ei,
    int* __restrict__ deg, int E) {
  int e = blockIdx.x * 256 + threadIdx.x;
  if (e < E) atomicAdd(&deg[ei[E + e]], 1);
}

// per-block exclusive scan of deg -> rowstart (local), block total -> bsum
__global__ __launch_bounds__(256) void k_part(const int* __restrict__ deg,
    int* __restrict__ rowstart, int* __restrict__ bsum, int N) {
  __shared__ int sc[256];
  int t = threadIdx.x;
  int i = blockIdx.x * 256 + t;
  int v = (i < N) ? deg[i] : 0;
  sc[t] = v;
  __syncthreads();
  for (int off = 1; off < 256; off <<= 1) {
    int u = (t >= off) ? sc[t - off] : 0;
    __syncthreads();
    sc[t] += u;
    __syncthreads();
  }
  if (i < N) rowstart[i] = sc[t] - v;
  if (t == 255) bsum[blockIdx.x] = sc[255];
}

// single block: exclusive scan of block sums -> boff; total -> rowstart[N]
__global__ __launch_bounds__(1024) void k_mid(const int* __restrict__ bsum,
    int* __restrict__ boff, int* __restrict__ rowstartN, int B) {
  __shared__ int sc[1024];
  int t = threadIdx.x;
  int v = (t < B) ? bsum[t] : 0;
  sc[t] = v;
  __syncthreads();
  for (int off = 1; off < 1024; off <<= 1) {
    int u = (t >= off) ? sc[t - off] : 0;
    __syncthreads();
    sc[t] += u;
    __syncthreads();
  }
  if (t < B) boff[t] = sc[t] - v;
  if (t == 1023) *rowstartN = sc[1023];
}

__global__ __launch_bounds__(256) void k_apply(int* __restrict__ rowstart,
    int* __restrict__ cursor, const int* __restrict__ boff, int N) {
  int i = blockIdx.x * 256 + threadIdx.x;
  if (i < N) {
    int r = rowstart[i] + boff[blockIdx.x];
    rowstart[i] = r;
    cursor[i] = r;
  }
}

__global__ __launch_bounds__(256) void k_fill(const int* __restrict__ ei,
    int* __restrict__ cursor, int* __restrict__ csr_src, int E) {
  int e = blockIdx.x * 256 + threadIdx.x;
  if (e < E) {
    int d = ei[E + e];
    int pos = atomicAdd(&cursor[d], 1);
    csr_src[pos] = ei[e];
  }
}

// ---------- conversions / packing ----------
__global__ __launch_bounds__(256) void k_convx(const float* __restrict__ x,
    ushort* __restrict__ xb, int total4) {
  int i = blockIdx.x * 256 + threadIdx.x;
  if (i >= total4) return;
  float4 v = ((const float4*)x)[i];
  ushort4 o;
  o.x = f2b(v.x); o.y = f2b(v.y); o.z = f2b(v.z); o.w = f2b(v.w);
  ((ushort4*)xb)[i] = o;
}

// pack W[k][n] (128x128 row-major) into B-fragment order for 16x16x32 MFMA:
// P[((q*8+c)*64 + l)*8 + j] = W[q*32 + (l>>4)*8 + j][c*16 + (l&15)]
__device__ __forceinline__ void packW_idx(int i, int& k, int& n) {
  int j = i & 7, l = (i >> 3) & 63, tile = i >> 9;
  int q = tile >> 3, c = tile & 7;
  k = q * 32 + ((l >> 4) << 3) + j;
  n = c * 16 + (l & 15);
}

__global__ __launch_bounds__(256) void k_packWlr(const float* __restrict__ Wl,
    const float* __restrict__ Wr, ushort* __restrict__ WlP,
    ushort* __restrict__ WrP) {
  int t = blockIdx.x * 256 + threadIdx.x;  // 32768
  int side = t >> 14;
  int i = t & 16383;
  int k, n;
  packW_idx(i, k, n);
  if (side) WrP[i] = f2b(Wr[k * DD + n]);
  else      WlP[i] = f2b(Wl[k * DD + n]);
}

__global__ __launch_bounds__(256) void k_packW2(const float* __restrict__ linW,
    const float* __restrict__ scale, const float* __restrict__ W2pp,
    ushort* __restrict__ W1P, ushort* __restrict__ W2P) {
  int t = blockIdx.x * 256 + threadIdx.x;  // 32768
  int side = t >> 14;
  int i = t & 16383;
  int k, n;
  packW_idx(i, k, n);
  if (side) W2P[i] = f2b(W2pp[k * DD + n]);
  else      W1P[i] = f2b(scale[k] * linW[k * DD + n]);
}

// ---------- MFMA GEMM: out_l/out_r (bf16) = A @ Wl/Wr + bias ----------
__global__ __launch_bounds__(256) void k_mm_lr(const ushort* __restrict__ xb,
    const ushort* __restrict__ WlP, const ushort* __restrict__ WrP,
    const float* __restrict__ bl, const float* __restrict__ br,
    ushort* __restrict__ xlb, ushort* __restrict__ xrb, int N) {
  __shared__ ushort sW[2][16384];
  {
    const uint4* a = (const uint4*)WlP;
    const uint4* b = (const uint4*)WrP;
    uint4* da = (uint4*)sW[0];
    uint4* db = (uint4*)sW[1];
    for (int i = threadIdx.x; i < 2048; i += 256) { da[i] = a[i]; db[i] = b[i]; }
  }
  __syncthreads();
  int lane = threadIdx.x & 63;
  int wv = threadIdx.x >> 6;
  int rbase = blockIdx.x * 64 + wv * 16;
  int arow = rbase + (lane & 15);
  if (arow >= N) arow = 0;  // stores masked below
  const ushort* ap = xb + (size_t)arow * DD + ((lane >> 4) << 3);
  s16x8 afr[4];
#pragma unroll
  for (int q = 0; q < 4; q++) afr[q] = *(const s16x8*)(ap + q * 32);
  f32x4 accL[8] = {}, accR[8] = {};
#pragma unroll
  for (int q = 0; q < 4; q++) {
#pragma unroll
    for (int c = 0; c < 8; c++) {
      s16x8 bL = *(const s16x8*)(sW[0] + ((q * 8 + c) * 64 + lane) * 8);
      accL[c] = __builtin_amdgcn_mfma_f32_16x16x32_bf16(afr[q], bL, accL[c], 0, 0, 0);
      s16x8 bR = *(const s16x8*)(sW[1] + ((q * 8 + c) * 64 + lane) * 8);
      accR[c] = __builtin_amdgcn_mfma_f32_16x16x32_bf16(afr[q], bR, accR[c], 0, 0, 0);
    }
  }
  int r0 = rbase + ((lane >> 4) << 2);
  int colb = lane & 15;
#pragma unroll
  for (int c = 0; c < 8; c++) {
    int col = c * 16 + colb;
    float vbl = bl[col], vbr = br[col];
#pragma unroll
    for (int r = 0; r < 4; r++) {
      int row = r0 + r;
      if (row < N) {
        xlb[(size_t)row * DD + col] = f2b(accL[c][r] + vbl);
        xrb[(size_t)row * DD + col] = f2b(accR[c][r] + vbr);
      }
    }
  }
}

// ---------- MFMA GEMM: z (f32 + bf16 copy) and v2 (f32) from hfeat ----------
__global__ __launch_bounds__(256) void k_mm_z(const ushort* __restrict__ hfb,
    const ushort* __restrict__ W1P, const ushort* __restrict__ W2P,
    const float* __restrict__ b1p, const float* __restrict__ b2pp,
    float* __restrict__ z, ushort* __restrict__ zb, float* __restrict__ v2,
    int N) {
  __shared__ ushort sW[2][16384];
  {
    const uint4* a = (const uint4*)W1P;
    const uint4* b = (const uint4*)W2P;
    uint4* da = (uint4*)sW[0];
    uint4* db = (uint4*)sW[1];
    for (int i = threadIdx.x; i < 2048; i += 256) { da[i] = a[i]; db[i] = b[i]; }
  }
  __syncthreads();
  int lane = threadIdx.x & 63;
  int wv = threadIdx.x >> 6;
  int rbase = blockIdx.x * 64 + wv * 16;
  int arow = rbase + (lane & 15);
  if (arow >= N) arow = 0;
  const ushort* ap = hfb + (size_t)arow * DD + ((lane >> 4) << 3);
  s16x8 afr[4];
#pragma unroll
  for (int q = 0; q < 4; q++) afr[q] = *(const s16x8*)(ap + q * 32);
  f32x4 acc1[8] = {}, acc2[8] = {};
#pragma unroll
  for (int q = 0; q < 4; q++) {
#pragma unroll
    for (int c = 0; c < 8; c++) {
      s16x8 b1 = *(const s16x8*)(sW[0] + ((q * 8 + c) * 64 + lane) * 8);
      acc1[c] = __builtin_amdgcn_mfma_f32_16x16x32_bf16(afr[q], b1, acc1[c], 0, 0, 0);
      s16x8 b2 = *(const s16x8*)(sW[1] + ((q * 8 + c) * 64 + lane) * 8);
      acc2[c] = __builtin_amdgcn_mfma_f32_16x16x32_bf16(afr[q], b2, acc2[c], 0, 0, 0);
    }
  }
  int r0 = rbase + ((lane >> 4) << 2);
  int colb = lane & 15;
#pragma unroll
  for (int c = 0; c < 8; c++) {
    int col = c * 16 + colb;
    float vb1 = b1p[col], vb2 = b2pp[col];
#pragma unroll
    for (int r = 0; r < 4; r++) {
      int row = r0 + r;
      if (row < N) {
        float zv = acc1[c][r] + vb1;
        z[(size_t)row * DD + col] = zv;
        zb[(size_t)row * DD + col] = f2b(zv);
        v2[(size_t)row * DD + col] = acc2[c][r] + vb2;
      }
    }
  }
}

// ---------- GAT aggregation: wave/node, online softmax, bf16 gathers ----------
__global__ __launch_bounds__(256) void k_agg(const ushort* __restrict__ xlb,
    const ushort* __restrict__ xrb, const int* __restrict__ rowstart,
    const int* __restrict__ csr_src, const float* __restrict__ att,
    const float* __restrict__ cb, ushort* __restrict__ hfb, int N) {
  int lane = threadIdx.x & 63;
  int d = (blockIdx.x * 256 + threadIdx.x) >> 6;
  if (d >= N) return;
  float2 a = ((const float2*)att)[lane];
  ushort2 rv = ((const ushort2*)(xrb + (size_t)d * DD))[lane];
  float2 r = {b2f(rv.x), b2f(rv.y)};
  ushort2 gv = ((const ushort2*)(xlb + (size_t)d * DD))[lane];
  float2 g = {b2f(gv.x), b2f(gv.y)};
  float t = lrelu(g.x + r.x) * a.x + lrelu(g.y + r.y) * a.y;
#pragma unroll
  for (int o = 4; o; o >>= 1) t += __shfl_xor(t, o);
  float m = t, den = 1.f;
  float2 acc = g;
  int i0 = rowstart[d], i1 = rowstart[d + 1];
  for (int i = i0; i < i1; i++) {
    int s = csr_src[i];
    gv = ((const ushort2*)(xlb + (size_t)s * DD))[lane];
    g.x = b2f(gv.x); g.y = b2f(gv.y);
    t = lrelu(g.x + r.x) * a.x + lrelu(g.y + r.y) * a.y;
#pragma unroll
    for (int o = 4; o; o >>= 1) t += __shfl_xor(t, o);
    if (t > m) {
      float sc = __expf(m - t);
      den = den * sc + 1.f;
      acc.x = acc.x * sc + g.x;
      acc.y = acc.y * sc + g.y;
      m = t;
    } else {
      float e = __expf(t - m);
      den += e;
      acc.x += e * g.x;
      acc.y += e * g.y;
    }
  }
  float2 c = ((const float2*)cb)[lane];
  float inv = 1.f / (den + 1e-16f);
  ushort2 o2;
  o2.x = f2b(fmaxf(fmaf(acc.x, inv, c.x), 0.f));
  o2.y = f2b(fmaxf(fmaf(acc.y, inv, c.y), 0.f));
  ((ushort2*)(hfb + (size_t)d * DD))[lane] = o2;
}

// ---------- BN stats from bf16 hfeat ----------
__global__ __launch_bounds__(256) void k_hbn2(const ushort* __restrict__ hfb,
    float* __restrict__ bnsum, int N) {
  int col = threadIdx.x & 127;
  float s = 0.f, ss = 0.f;
  for (int r = blockIdx.x * 2 + (threadIdx.x >> 7); r < N; r += gridDim.x * 2) {
    float v = b2f(hfb[(size_t)r * DD + col]);
    s += v;
    ss += v * v;
  }
  __shared__ float ls[256], lss[256];
  ls[threadIdx.x] = s;
  lss[threadIdx.x] = ss;
  __syncthreads();
  if (threadIdx.x < 128) {
    atomAddF(&bnsum[col], ls[threadIdx.x] + ls[threadIdx.x + 128]);
    atomAddF(&bnsum[DD + col], lss[threadIdx.x] + lss[threadIdx.x + 128]);
  }
}

// ---------- BN fold ----------
__global__ __launch_bounds__(128) void k_bnfold(const float* __restrict__ bnsum,
    const float* __restrict__ gamma, const float* __restrict__ beta,
    const float* __restrict__ linW, const float* __restrict__ linb,
    const float* __restrict__ dec2W, const float* __restrict__ dec2b,
    float* __restrict__ scale, float* __restrict__ shift,
    float* __restrict__ b1p, float* __restrict__ b2pp, int N) {
  int t = threadIdx.x;
  __shared__ float sshift[DD], sb1[DD];
  float mean = bnsum[t] / (float)N;
  float var = bnsum[DD + t] / (float)N - mean * mean;
  float sc = gamma[t] / sqrtf(var + 1e-5f);
  float sh = beta[t] - mean * sc;
  scale[t] = sc;
  shift[t] = sh;
  sshift[t] = sh;
  __syncthreads();
  float b1 = linb[t];
  for (int k = 0; k < DD; k++) b1 += sshift[k] * linW[k * DD + t];
  b1p[t] = b1;
  sb1[t] = b1;
  __syncthreads();
  float b2 = dec2b[t];
  for (int k = 0; k < DD; k++) b2 += sb1[k] * dec2W[k * DD + t];
  b2pp[t] = b2;
}

// W2''[d][j] = scale[d] * sum_k linW[d][k]*dec2W[k][j]
__global__ __launch_bounds__(256) void k_w2pp(const float* __restrict__ scale,
    const float* __restrict__ linW, const float* __restrict__ dec2W,
    float* __restrict__ W2pp) {
  int t = blockIdx.x * 256 + threadIdx.x;
  int dd = t >> 7, j = t & 127;
  float s = 0.f;
  for (int k = 0; k < DD; k++) s += linW[dd * DD + k] * dec2W[k * DD + j];
  W2pp[t] = scale[dd] * s;
}

// ---------- edge decoder: bf16 z gathers ----------
__global__ __launch_bounds__(256) void k_edge(const ushort* __restrict__ zb,
    const int* __restrict__ ei, const float* __restrict__ ae,
    const float* __restrict__ be, float* __restrict__ v1, int E) {
  int lane = threadIdx.x & 63;
  int wid = (blockIdx.x * 256 + threadIdx.x) >> 6;
  int nw = (gridDim.x * 256) >> 6;
  float a = fmaxf(ae[0], 0.f), b = be[0];
  for (int e = wid; e < E; e += nw) {
    int s = ei[e], d = ei[E + e];
    ushort2 zs = ((const ushort2*)(zb + (size_t)s * DD))[lane];
    ushort2 zd = ((const ushort2*)(zb + (size_t)d * DD))[lane];
    float dx = b2f(zs.x) - b2f(zd.x), dy = b2f(zs.y) - b2f(zd.y);
    float v = dx * dx + dy * dy;
#pragma unroll
    for (int o = 32; o; o >>= 1) v += __shfl_xor(v, o);
    if (lane == 0) v1[e] = 1.f / (1.f + __expf(fmaf(a, v, b)));
  }
}

extern "C" void kernel_launch(void* const* d_in, const int* in_sizes, int n_in,
                              void* d_out, int out_size, void* d_ws, size_t ws_size,
                              hipStream_t stream) {
  const float* x = (const float*)d_in[0];
  const int* ei = (const int*)d_in[1];
  const float* Wl = (const float*)d_in[2];
  const float* bl = (const float*)d_in[3];
  const float* Wr = (const float*)d_in[4];
  const float* br = (const float*)d_in[5];
  const float* att = (const float*)d_in[6];
  const float* cb = (const float*)d_in[7];
  const float* gamma = (const float*)d_in[8];
  const float* beta = (const float*)d_in[9];
  const float* linW = (const float*)d_in[10];
  const float* linb = (const float*)d_in[11];
  const float* ae = (const float*)d_in[12];
  const float* be = (const float*)d_in[13];
  const float* dec2W = (const float*)d_in[14];
  const float* dec2b = (const float*)d_in[15];

  int N = in_sizes[0] / DD;
  int E = in_sizes[1] / 2;
  size_t ND = (size_t)N * DD;
  int B = (N + 255) / 256;

  char* wsb = (char*)d_ws;
  size_t o = 0;
  auto alloc = [&](size_t bytes) {
    void* p = wsb + o;
    o += (bytes + 15) & ~(size_t)15;
    return p;
  };
  ushort* xb  = (ushort*)alloc(ND * 2);
  ushort* xlb = (ushort*)alloc(ND * 2);
  ushort* xrb = (ushort*)alloc(ND * 2);
  ushort* hfb = (ushort*)alloc(ND * 2);
  ushort* zbb = (ushort*)alloc(ND * 2);
  ushort* WlP = (ushort*)alloc(DD * DD * 2);
  ushort* WrP = (ushort*)alloc(DD * DD * 2);
  ushort* W1P = (ushort*)alloc(DD * DD * 2);
  ushort* W2P = (ushort*)alloc(DD * DD * 2);
  float* bnsum = (float*)alloc(2 * DD * 4);
  float* scale = (float*)alloc(DD * 4);
  float* shift = (float*)alloc(DD * 4);
  float* b1p   = (float*)alloc(DD * 4);
  float* b2pp  = (float*)alloc(DD * 4);
  float* W2pp  = (float*)alloc(DD * DD * 4);
  int* deg      = (int*)alloc((size_t)(N + 1) * 4);
  int* rowstart = (int*)alloc((size_t)(N + 1) * 4);
  int* cursor   = (int*)alloc((size_t)N * 4);
  int* bsum     = (int*)alloc((size_t)B * 4);
  int* boff     = (int*)alloc((size_t)B * 4);
  int* csr_src  = (int*)alloc((size_t)E * 4);

  float* z = (float*)d_out;
  float* v1 = z + ND;
  float* v2 = v1 + E;

  hipMemsetAsync(deg, 0, (size_t)(N + 1) * 4, stream);
  hipMemsetAsync(bnsum, 0, 2 * DD * 4, stream);

  k_deg<<<(E + 255) / 256, 256, 0, stream>>>(ei, deg, E);
  k_part<<<B, 256, 0, stream>>>(deg, rowstart, bsum, N);
  k_mid<<<1, 1024, 0, stream>>>(bsum, boff, rowstart + N, B);
  k_apply<<<B, 256, 0, stream>>>(rowstart, cursor, boff, N);
  k_fill<<<(E + 255) / 256, 256, 0, stream>>>(ei, cursor, csr_src, E);
  int total4 = (int)(ND / 4);
  k_convx<<<(total4 + 255) / 256, 256, 0, stream>>>(x, xb, total4);
  k_packWlr<<<128, 256, 0, stream>>>(Wl, Wr, WlP, WrP);
  k_mm_lr<<<(N + 63) / 64, 256, 0, stream>>>(xb, WlP, WrP, bl, br, xlb, xrb, N);
  k_agg<<<(N + 3) / 4, 256, 0, stream>>>(xlb, xrb, rowstart, csr_src, att, cb,
                                         hfb, N);
  k_hbn2<<<256, 256, 0, stream>>>(hfb, bnsum, N);
  k_bnfold<<<1, 128, 0, stream>>>(bnsum, gamma, beta, linW, linb, dec2W, dec2b,
                                  scale, shift, b1p, b2pp, N);
  k_w2pp<<<64, 256, 0, stream>>>(scale, linW, dec2W, W2pp);
  k_packW2<<<128, 256, 0, stream>>>(linW, scale, W2pp, W1P, W2P);
  k_mm_z<<<(N + 63) / 64, 256, 0, stream>>>(hfb, W1P, W2P, b1p, b2pp, z, zbb,
                                            v2, N);
  k_edge<<<2048, 256, 0, stream>>>(zbb, ei, ae, be, v1, E);
}

// Round 5
// 306.959 us; speedup vs baseline: 3.5570x; 1.3021x over previous
//
#include <hip/hip_runtime.h>

#define DD 128
#define HH 8

typedef float f32x4 __attribute__((ext_vector_type(4)));
typedef short s16x8 __attribute__((ext_vector_type(8)));

__device__ __forceinline__ ushort f2b(float f) {
  unsigned u = __float_as_uint(f);
  unsigned r = u + 0x7fffu + ((u >> 16) & 1u);
  return (ushort)(r >> 16);
}
__device__ __forceinline__ float b2f(ushort b) {
  return __uint_as_float(((unsigned)b) << 16);
}
__device__ __forceinline__ void atomAddF(float* p, float v) {
#if defined(__HIP_DEVICE_COMPILE__)
  unsafeAtomicAdd(p, v);
#else
  atomicAdd(p, v);
#endif
}
__device__ __forceinline__ float lrelu(float v) { return v > 0.f ? v : 0.2f * v; }

// ---------- CSR build ----------
__global__ __launch_bounds__(256) void k_deg(const int* __restrict__ ei,
    int* __restrict__ deg, int E) {
  int e = blockIdx.x * 256 + threadIdx.x;
  if (e < E) atomicAdd(&deg[ei[E + e]], 1);
}

__global__ __launch_bounds__(256) void k_part(const int* __restrict__ deg,
    int* __restrict__ rowstart, int* __restrict__ bsum, int N) {
  __shared__ int sc[256];
  int t = threadIdx.x;
  int i = blockIdx.x * 256 + t;
  int v = (i < N) ? deg[i] : 0;
  sc[t] = v;
  __syncthreads();
  for (int off = 1; off < 256; off <<= 1) {
    int u = (t >= off) ? sc[t - off] : 0;
    __syncthreads();
    sc[t] += u;
    __syncthreads();
  }
  if (i < N) rowstart[i] = sc[t] - v;
  if (t == 255) bsum[blockIdx.x] = sc[255];
}

__global__ __launch_bounds__(1024) void k_mid(const int* __restrict__ bsum,
    int* __restrict__ boff, int* __restrict__ rowstartN, int B) {
  __shared__ int sc[1024];
  int t = threadIdx.x;
  int v = (t < B) ? bsum[t] : 0;
  sc[t] = v;
  __syncthreads();
  for (int off = 1; off < 1024; off <<= 1) {
    int u = (t >= off) ? sc[t - off] : 0;
    __syncthreads();
    sc[t] += u;
    __syncthreads();
  }
  if (t < B) boff[t] = sc[t] - v;
  if (t == 1023) *rowstartN = sc[1023];
}

__global__ __launch_bounds__(256) void k_apply(int* __restrict__ rowstart,
    int* __restrict__ cursor, const int* __restrict__ boff, int N) {
  int i = blockIdx.x * 256 + threadIdx.x;
  if (i < N) {
    int r = rowstart[i] + boff[blockIdx.x];
    rowstart[i] = r;
    cursor[i] = r;
  }
}

__global__ __launch_bounds__(256) void k_fill(const int* __restrict__ ei,
    int* __restrict__ cursor, int* __restrict__ csr_src, int E) {
  int e = blockIdx.x * 256 + threadIdx.x;
  if (e < E) {
    int d = ei[E + e];
    int pos = atomicAdd(&cursor[d], 1);
    csr_src[pos] = ei[e];
  }
}

// ---------- conversions / packing ----------
__global__ __launch_bounds__(256) void k_convx(const float* __restrict__ x,
    ushort* __restrict__ xb, int total4) {
  int i = blockIdx.x * 256 + threadIdx.x;
  if (i >= total4) return;
  float4 v = ((const float4*)x)[i];
  ushort4 o;
  o.x = f2b(v.x); o.y = f2b(v.y); o.z = f2b(v.z); o.w = f2b(v.w);
  ((ushort4*)xb)[i] = o;
}

// pack W[k][n] (128x128 row-major) into B-fragment order for 16x16x32 MFMA:
// P[((q*8+c)*64 + l)*8 + j] = W[q*32 + (l>>4)*8 + j][c*16 + (l&15)]
__device__ __forceinline__ void packW_idx(int i, int& k, int& n) {
  int j = i & 7, l = (i >> 3) & 63, tile = i >> 9;
  int q = tile >> 3, c = tile & 7;
  k = q * 32 + ((l >> 4) << 3) + j;
  n = c * 16 + (l & 15);
}

__global__ __launch_bounds__(256) void k_packWlr(const float* __restrict__ Wl,
    const float* __restrict__ Wr, ushort* __restrict__ WlP,
    ushort* __restrict__ WrP) {
  int t = blockIdx.x * 256 + threadIdx.x;  // 32768
  int side = t >> 14;
  int i = t & 16383;
  int k, n;
  packW_idx(i, k, n);
  if (side) WrP[i] = f2b(Wr[k * DD + n]);
  else      WlP[i] = f2b(Wl[k * DD + n]);
}

__global__ __launch_bounds__(256) void k_packW2(const float* __restrict__ linW,
    const float* __restrict__ scale, const float* __restrict__ W2pp,
    ushort* __restrict__ W1P, ushort* __restrict__ W2P) {
  int t = blockIdx.x * 256 + threadIdx.x;  // 32768
  int side = t >> 14;
  int i = t & 16383;
  int k, n;
  packW_idx(i, k, n);
  if (side) W2P[i] = f2b(W2pp[k * DD + n]);
  else      W1P[i] = f2b(scale[k] * linW[k * DD + n]);
}

// ---------- MFMA GEMM: out_l/out_r (bf16) = A @ Wl/Wr + bias ----------
__global__ __launch_bounds__(256) void k_mm_lr(const ushort* __restrict__ xb,
    const ushort* __restrict__ WlP, const ushort* __restrict__ WrP,
    const float* __restrict__ bl, const float* __restrict__ br,
    ushort* __restrict__ xlb, ushort* __restrict__ xrb, int N) {
  __shared__ ushort sW[2][16384];
  {
    const uint4* a = (const uint4*)WlP;
    const uint4* b = (const uint4*)WrP;
    uint4* da = (uint4*)sW[0];
    uint4* db = (uint4*)sW[1];
    for (int i = threadIdx.x; i < 2048; i += 256) { da[i] = a[i]; db[i] = b[i]; }
  }
  __syncthreads();
  int lane = threadIdx.x & 63;
  int wv = threadIdx.x >> 6;
  int rbase = blockIdx.x * 64 + wv * 16;
  int arow = rbase + (lane & 15);
  if (arow >= N) arow = 0;  // stores masked below
  const ushort* ap = xb + (size_t)arow * DD + ((lane >> 4) << 3);
  s16x8 afr[4];
#pragma unroll
  for (int q = 0; q < 4; q++) afr[q] = *(const s16x8*)(ap + q * 32);
  f32x4 accL[8] = {}, accR[8] = {};
#pragma unroll
  for (int q = 0; q < 4; q++) {
#pragma unroll
    for (int c = 0; c < 8; c++) {
      s16x8 bL = *(const s16x8*)(sW[0] + ((q * 8 + c) * 64 + lane) * 8);
      accL[c] = __builtin_amdgcn_mfma_f32_16x16x32_bf16(afr[q], bL, accL[c], 0, 0, 0);
      s16x8 bR = *(const s16x8*)(sW[1] + ((q * 8 + c) * 64 + lane) * 8);
      accR[c] = __builtin_amdgcn_mfma_f32_16x16x32_bf16(afr[q], bR, accR[c], 0, 0, 0);
    }
  }
  int r0 = rbase + ((lane >> 4) << 2);
  int colb = lane & 15;
#pragma unroll
  for (int c = 0; c < 8; c++) {
    int col = c * 16 + colb;
    float vbl = bl[col], vbr = br[col];
#pragma unroll
    for (int r = 0; r < 4; r++) {
      int row = r0 + r;
      if (row < N) {
        xlb[(size_t)row * DD + col] = f2b(accL[c][r] + vbl);
        xrb[(size_t)row * DD + col] = f2b(accR[c][r] + vbr);
      }
    }
  }
}

// ---------- MFMA GEMM: z (f32 + bf16 copy) and v2 (f32) from hfeat ----------
__global__ __launch_bounds__(256) void k_mm_z(const ushort* __restrict__ hfb,
    const ushort* __restrict__ W1P, const ushort* __restrict__ W2P,
    const float* __restrict__ b1p, const float* __restrict__ b2pp,
    float* __restrict__ z, ushort* __restrict__ zb, float* __restrict__ v2,
    int N) {
  __shared__ ushort sW[2][16384];
  {
    const uint4* a = (const uint4*)W1P;
    const uint4* b = (const uint4*)W2P;
    uint4* da = (uint4*)sW[0];
    uint4* db = (uint4*)sW[1];
    for (int i = threadIdx.x; i < 2048; i += 256) { da[i] = a[i]; db[i] = b[i]; }
  }
  __syncthreads();
  int lane = threadIdx.x & 63;
  int wv = threadIdx.x >> 6;
  int rbase = blockIdx.x * 64 + wv * 16;
  int arow = rbase + (lane & 15);
  if (arow >= N) arow = 0;
  const ushort* ap = hfb + (size_t)arow * DD + ((lane >> 4) << 3);
  s16x8 afr[4];
#pragma unroll
  for (int q = 0; q < 4; q++) afr[q] = *(const s16x8*)(ap + q * 32);
  f32x4 acc1[8] = {}, acc2[8] = {};
#pragma unroll
  for (int q = 0; q < 4; q++) {
#pragma unroll
    for (int c = 0; c < 8; c++) {
      s16x8 b1 = *(const s16x8*)(sW[0] + ((q * 8 + c) * 64 + lane) * 8);
      acc1[c] = __builtin_amdgcn_mfma_f32_16x16x32_bf16(afr[q], b1, acc1[c], 0, 0, 0);
      s16x8 b2 = *(const s16x8*)(sW[1] + ((q * 8 + c) * 64 + lane) * 8);
      acc2[c] = __builtin_amdgcn_mfma_f32_16x16x32_bf16(afr[q], b2, acc2[c], 0, 0, 0);
    }
  }
  int r0 = rbase + ((lane >> 4) << 2);
  int colb = lane & 15;
#pragma unroll
  for (int c = 0; c < 8; c++) {
    int col = c * 16 + colb;
    float vb1 = b1p[col], vb2 = b2pp[col];
#pragma unroll
    for (int r = 0; r < 4; r++) {
      int row = r0 + r;
      if (row < N) {
        float zv = acc1[c][r] + vb1;
        z[(size_t)row * DD + col] = zv;
        zb[(size_t)row * DD + col] = f2b(zv);
        v2[(size_t)row * DD + col] = acc2[c][r] + vb2;
      }
    }
  }
}

// ---------- GAT aggregation: wave/node, 4-state online softmax ----------
__global__ __launch_bounds__(256) void k_agg(const ushort* __restrict__ xlb,
    const ushort* __restrict__ xrb, const int* __restrict__ rowstart,
    const int* __restrict__ csr_src, const float* __restrict__ att,
    const float* __restrict__ cb, ushort* __restrict__ hfb, int N) {
  int lane = threadIdx.x & 63;
  int d = (blockIdx.x * 256 + threadIdx.x) >> 6;
  if (d >= N) return;
  float2 a = ((const float2*)att)[lane];
  ushort2 rv = ((const ushort2*)(xrb + (size_t)d * DD))[lane];
  float2 r = {b2f(rv.x), b2f(rv.y)};
  // state 0 seeded with self-loop (src = dst)
  ushort2 gv = ((const ushort2*)(xlb + (size_t)d * DD))[lane];
  float2 g0 = {b2f(gv.x), b2f(gv.y)};
  float t0 = lrelu(g0.x + r.x) * a.x + lrelu(g0.y + r.y) * a.y;
#pragma unroll
  for (int o = 4; o; o >>= 1) t0 += __shfl_xor(t0, o);
  float m0 = t0, den0 = 1.f;
  float2 acc0 = g0;
  float m1 = -INFINITY, den1 = 0.f;
  float2 acc1 = {0.f, 0.f};
  float m2 = -INFINITY, den2 = 0.f;
  float2 acc2 = {0.f, 0.f};
  float m3 = -INFINITY, den3 = 0.f;
  float2 acc3 = {0.f, 0.f};
  int i0 = rowstart[d], i1 = rowstart[d + 1];
  int i = i0;
  for (; i + 4 <= i1; i += 4) {
    int s0 = csr_src[i], s1 = csr_src[i + 1];
    int s2 = csr_src[i + 2], s3 = csr_src[i + 3];
    ushort2 va = ((const ushort2*)(xlb + (size_t)s0 * DD))[lane];
    ushort2 vb = ((const ushort2*)(xlb + (size_t)s1 * DD))[lane];
    ushort2 vc = ((const ushort2*)(xlb + (size_t)s2 * DD))[lane];
    ushort2 vd = ((const ushort2*)(xlb + (size_t)s3 * DD))[lane];
    float2 ga = {b2f(va.x), b2f(va.y)};
    float2 gb = {b2f(vb.x), b2f(vb.y)};
    float2 gc = {b2f(vc.x), b2f(vc.y)};
    float2 gd = {b2f(vd.x), b2f(vd.y)};
    float ta = lrelu(ga.x + r.x) * a.x + lrelu(ga.y + r.y) * a.y;
    float tb = lrelu(gb.x + r.x) * a.x + lrelu(gb.y + r.y) * a.y;
    float tc = lrelu(gc.x + r.x) * a.x + lrelu(gc.y + r.y) * a.y;
    float td = lrelu(gd.x + r.x) * a.x + lrelu(gd.y + r.y) * a.y;
#pragma unroll
    for (int o = 4; o; o >>= 1) {
      ta += __shfl_xor(ta, o);
      tb += __shfl_xor(tb, o);
      tc += __shfl_xor(tc, o);
      td += __shfl_xor(td, o);
    }
    float mn, sc, e;
    mn = fmaxf(m0, ta); sc = __expf(m0 - mn); e = __expf(ta - mn);
    den0 = den0 * sc + e;
    acc0.x = acc0.x * sc + e * ga.x; acc0.y = acc0.y * sc + e * ga.y; m0 = mn;
    mn = fmaxf(m1, tb); sc = __expf(m1 - mn); e = __expf(tb - mn);
    den1 = den1 * sc + e;
    acc1.x = acc1.x * sc + e * gb.x; acc1.y = acc1.y * sc + e * gb.y; m1 = mn;
    mn = fmaxf(m2, tc); sc = __expf(m2 - mn); e = __expf(tc - mn);
    den2 = den2 * sc + e;
    acc2.x = acc2.x * sc + e * gc.x; acc2.y = acc2.y * sc + e * gc.y; m2 = mn;
    mn = fmaxf(m3, td); sc = __expf(m3 - mn); e = __expf(td - mn);
    den3 = den3 * sc + e;
    acc3.x = acc3.x * sc + e * gd.x; acc3.y = acc3.y * sc + e * gd.y; m3 = mn;
  }
  for (; i < i1; i++) {
    int s = csr_src[i];
    ushort2 va = ((const ushort2*)(xlb + (size_t)s * DD))[lane];
    float2 ga = {b2f(va.x), b2f(va.y)};
    float ta = lrelu(ga.x + r.x) * a.x + lrelu(ga.y + r.y) * a.y;
#pragma unroll
    for (int o = 4; o; o >>= 1) ta += __shfl_xor(ta, o);
    float mn = fmaxf(m0, ta);
    float sc = __expf(m0 - mn);
    float e = __expf(ta - mn);
    den0 = den0 * sc + e;
    acc0.x = acc0.x * sc + e * ga.x;
    acc0.y = acc0.y * sc + e * ga.y;
    m0 = mn;
  }
  // exact merge of the 4 states
  float M = fmaxf(fmaxf(m0, m1), fmaxf(m2, m3));
  float w0 = __expf(m0 - M), w1 = __expf(m1 - M);
  float w2 = __expf(m2 - M), w3 = __expf(m3 - M);
  float den = den0 * w0 + den1 * w1 + den2 * w2 + den3 * w3;
  float ax = acc0.x * w0 + acc1.x * w1 + acc2.x * w2 + acc3.x * w3;
  float ay = acc0.y * w0 + acc1.y * w1 + acc2.y * w2 + acc3.y * w3;
  float2 c = ((const float2*)cb)[lane];
  float inv = 1.f / (den + 1e-16f);
  ushort2 o2;
  o2.x = f2b(fmaxf(fmaf(ax, inv, c.x), 0.f));
  o2.y = f2b(fmaxf(fmaf(ay, inv, c.y), 0.f));
  ((ushort2*)(hfb + (size_t)d * DD))[lane] = o2;
}

// ---------- BN stats from bf16 hfeat ----------
__global__ __launch_bounds__(256) void k_hbn2(const ushort* __restrict__ hfb,
    float* __restrict__ bnsum, int N) {
  int col = threadIdx.x & 127;
  float s = 0.f, ss = 0.f;
  for (int r = blockIdx.x * 2 + (threadIdx.x >> 7); r < N; r += gridDim.x * 2) {
    float v = b2f(hfb[(size_t)r * DD + col]);
    s += v;
    ss += v * v;
  }
  __shared__ float ls[256], lss[256];
  ls[threadIdx.x] = s;
  lss[threadIdx.x] = ss;
  __syncthreads();
  if (threadIdx.x < 128) {
    atomAddF(&bnsum[col], ls[threadIdx.x] + ls[threadIdx.x + 128]);
    atomAddF(&bnsum[DD + col], lss[threadIdx.x] + lss[threadIdx.x + 128]);
  }
}

// ---------- BN fold ----------
__global__ __launch_bounds__(128) void k_bnfold(const float* __restrict__ bnsum,
    const float* __restrict__ gamma, const float* __restrict__ beta,
    const float* __restrict__ linW, const float* __restrict__ linb,
    const float* __restrict__ dec2W, const float* __restrict__ dec2b,
    float* __restrict__ scale, float* __restrict__ shift,
    float* __restrict__ b1p, float* __restrict__ b2pp, int N) {
  int t = threadIdx.x;
  __shared__ float sshift[DD], sb1[DD];
  float mean = bnsum[t] / (float)N;
  float var = bnsum[DD + t] / (float)N - mean * mean;
  float sc = gamma[t] / sqrtf(var + 1e-5f);
  float sh = beta[t] - mean * sc;
  scale[t] = sc;
  shift[t] = sh;
  sshift[t] = sh;
  __syncthreads();
  float b1 = linb[t];
  for (int k = 0; k < DD; k++) b1 += sshift[k] * linW[k * DD + t];
  b1p[t] = b1;
  sb1[t] = b1;
  __syncthreads();
  float b2 = dec2b[t];
  for (int k = 0; k < DD; k++) b2 += sb1[k] * dec2W[k * DD + t];
  b2pp[t] = b2;
}

// W2''[d][j] = scale[d] * sum_k linW[d][k]*dec2W[k][j]
__global__ __launch_bounds__(256) void k_w2pp(const float* __restrict__ scale,
    const float* __restrict__ linW, const float* __restrict__ dec2W,
    float* __restrict__ W2pp) {
  int t = blockIdx.x * 256 + threadIdx.x;
  int dd = t >> 7, j = t & 127;
  float s = 0.f;
  for (int k = 0; k < DD; k++) s += linW[dd * DD + k] * dec2W[k * DD + j];
  W2pp[t] = scale[dd] * s;
}

// ---------- edge decoder: 4 edges/wave, 16 lanes x 8ch, packed bf16 ----------
__global__ __launch_bounds__(256) void k_edge(const ushort* __restrict__ zb,
    const int* __restrict__ ei, const float* __restrict__ ae,
    const float* __restrict__ be, float* __restrict__ v1, int E) {
  int lane = threadIdx.x & 63;
  int sub = lane >> 4;   // edge within quad
  int cl = lane & 15;    // channel-lane (8 channels each)
  int wid = (blockIdx.x * 256 + threadIdx.x) >> 6;
  int nw = (gridDim.x * 256) >> 6;
  int nq = (E + 3) >> 2;
  float a = fmaxf(ae[0], 0.f), b = be[0];
  for (int q = wid; q < nq; q += nw) {
    int e = q * 4 + sub;
    bool ok = e < E;
    int ec = ok ? e : 0;
    int s = ei[ec], d = ei[E + ec];
    uint4 zs = *(const uint4*)(zb + (size_t)s * DD + cl * 8);
    uint4 zd = *(const uint4*)(zb + (size_t)d * DD + cl * 8);
    float v = 0.f;
    float dl, dh;
    dl = __uint_as_float(zs.x << 16) - __uint_as_float(zd.x << 16);
    dh = __uint_as_float(zs.x & 0xffff0000u) - __uint_as_float(zd.x & 0xffff0000u);
    v += dl * dl + dh * dh;
    dl = __uint_as_float(zs.y << 16) - __uint_as_float(zd.y << 16);
    dh = __uint_as_float(zs.y & 0xffff0000u) - __uint_as_float(zd.y & 0xffff0000u);
    v += dl * dl + dh * dh;
    dl = __uint_as_float(zs.z << 16) - __uint_as_float(zd.z << 16);
    dh = __uint_as_float(zs.z & 0xffff0000u) - __uint_as_float(zd.z & 0xffff0000u);
    v += dl * dl + dh * dh;
    dl = __uint_as_float(zs.w << 16) - __uint_as_float(zd.w << 16);
    dh = __uint_as_float(zs.w & 0xffff0000u) - __uint_as_float(zd.w & 0xffff0000u);
    v += dl * dl + dh * dh;
#pragma unroll
    for (int o = 8; o; o >>= 1) v += __shfl_xor(v, o);
    if (cl == 0 && ok) v1[e] = 1.f / (1.f + __expf(fmaf(a, v, b)));
  }
}

extern "C" void kernel_launch(void* const* d_in, const int* in_sizes, int n_in,
                              void* d_out, int out_size, void* d_ws, size_t ws_size,
                              hipStream_t stream) {
  const float* x = (const float*)d_in[0];
  const int* ei = (const int*)d_in[1];
  const float* Wl = (const float*)d_in[2];
  const float* bl = (const float*)d_in[3];
  const float* Wr = (const float*)d_in[4];
  const float* br = (const float*)d_in[5];
  const float* att = (const float*)d_in[6];
  const float* cb = (const float*)d_in[7];
  const float* gamma = (const float*)d_in[8];
  const float* beta = (const float*)d_in[9];
  const float* linW = (const float*)d_in[10];
  const float* linb = (const float*)d_in[11];
  const float* ae = (const float*)d_in[12];
  const float* be = (const float*)d_in[13];
  const float* dec2W = (const float*)d_in[14];
  const float* dec2b = (const float*)d_in[15];

  int N = in_sizes[0] / DD;
  int E = in_sizes[1] / 2;
  size_t ND = (size_t)N * DD;
  int B = (N + 255) / 256;

  char* wsb = (char*)d_ws;
  size_t o = 0;
  auto alloc = [&](size_t bytes) {
    void* p = wsb + o;
    o += (bytes + 15) & ~(size_t)15;
    return p;
  };
  ushort* xb  = (ushort*)alloc(ND * 2);
  ushort* xlb = (ushort*)alloc(ND * 2);
  ushort* xrb = (ushort*)alloc(ND * 2);
  ushort* hfb = (ushort*)alloc(ND * 2);
  ushort* zbb = (ushort*)alloc(ND * 2);
  ushort* WlP = (ushort*)alloc(DD * DD * 2);
  ushort* WrP = (ushort*)alloc(DD * DD * 2);
  ushort* W1P = (ushort*)alloc(DD * DD * 2);
  ushort* W2P = (ushort*)alloc(DD * DD * 2);
  float* bnsum = (float*)alloc(2 * DD * 4);
  float* scale = (float*)alloc(DD * 4);
  float* shift = (float*)alloc(DD * 4);
  float* b1p   = (float*)alloc(DD * 4);
  float* b2pp  = (float*)alloc(DD * 4);
  float* W2pp  = (float*)alloc(DD * DD * 4);
  int* deg      = (int*)alloc((size_t)(N + 1) * 4);
  int* rowstart = (int*)alloc((size_t)(N + 1) * 4);
  int* cursor   = (int*)alloc((size_t)N * 4);
  int* bsum     = (int*)alloc((size_t)B * 4);
  int* boff     = (int*)alloc((size_t)B * 4);
  int* csr_src  = (int*)alloc((size_t)E * 4);

  float* z = (float*)d_out;
  float* v1 = z + ND;
  float* v2 = v1 + E;

  hipMemsetAsync(deg, 0, (size_t)(N + 1) * 4, stream);
  hipMemsetAsync(bnsum, 0, 2 * DD * 4, stream);

  k_deg<<<(E + 255) / 256, 256, 0, stream>>>(ei, deg, E);
  k_part<<<B, 256, 0, stream>>>(deg, rowstart, bsum, N);
  k_mid<<<1, 1024, 0, stream>>>(bsum, boff, rowstart + N, B);
  k_apply<<<B, 256, 0, stream>>>(rowstart, cursor, boff, N);
  k_fill<<<(E + 255) / 256, 256, 0, stream>>>(ei, cursor, csr_src, E);
  int total4 = (int)(ND / 4);
  k_convx<<<(total4 + 255) / 256, 256, 0, stream>>>(x, xb, total4);
  k_packWlr<<<128, 256, 0, stream>>>(Wl, Wr, WlP, WrP);
  k_mm_lr<<<(N + 63) / 64, 256, 0, stream>>>(xb, WlP, WrP, bl, br, xlb, xrb, N);
  k_agg<<<(N + 3) / 4, 256, 0, stream>>>(xlb, xrb, rowstart, csr_src, att, cb,
                                         hfb, N);
  k_hbn2<<<256, 256, 0, stream>>>(hfb, bnsum, N);
  k_bnfold<<<1, 128, 0, stream>>>(bnsum, gamma, beta, linW, linb, dec2W, dec2b,
                                  scale, shift, b1p, b2pp, N);
  k_w2pp<<<64, 256, 0, stream>>>(scale, linW, dec2W, W2pp);
  k_packW2<<<128, 256, 0, stream>>>(linW, scale, W2pp, W1P, W2P);
  k_mm_z<<<(N + 63) / 64, 256, 0, stream>>>(hfb, W1P, W2P, b1p, b2pp, z, zbb,
                                            v2, N);
  k_edge<<<2048, 256, 0, stream>>>(zbb, ei, ae, be, v1, E);
}